// Round 14
// baseline (3291.843 us; speedup 1.0000x reference)
//
#include <hip/hip_runtime.h>

#define CDIV(a,b) (((a)+(b)-1)/(b))

static const int N_ATOM = 131072, N_FRAG = 32768, N_EDGE = 262144,
                 N_FEDGE = 65536, N_MEM = 196608, BATCH = 4096, H = 256;
static const int NREP = 16;   // stat atomic replicas

typedef unsigned short ushort_t;
typedef _Float16 half8_t __attribute__((ext_vector_type(8)));
typedef float    floatx4 __attribute__((ext_vector_type(4)));

struct PanelsIn  { const ushort_t* p[4]; };
struct PanelsOut { ushort_t* p[4]; };

__device__ __forceinline__ float h2f(ushort_t u) {
    _Float16 h; __builtin_memcpy(&h, &u, 2); return (float)h;
}
__device__ __forceinline__ ushort_t f2h(float f) {
    _Float16 h = (_Float16)f; ushort_t u; __builtin_memcpy(&u, &h, 2); return u;
}

// async global->LDS, 16B per lane. lds base must be wave-uniform; HW adds lane*16.
__device__ __forceinline__ void load_lds16(const ushort_t* g, ushort_t* l) {
    __builtin_amdgcn_global_load_lds(
        (const __attribute__((address_space(1))) unsigned int*)g,
        (__attribute__((address_space(3))) unsigned int*)l, 16, 0, 0);
}

__global__ void fill_const(float* p, long n, float v) {
    long t = (long)blockIdx.x * blockDim.x + threadIdx.x;
    long stride = (long)gridDim.x * blockDim.x;
    for (; t < n; t += stride) p[t] = v;
}

// f32 -> f16 bulk convert (n % 4 == 0)
__global__ void conv_f2h(const float* __restrict__ in, ushort_t* __restrict__ out, long n)
{
    long t = (long)blockIdx.x * 256 + threadIdx.x;
    long stride = (long)gridDim.x * 256;
    for (long i = t; i < n / 4; i += stride) {
        float4 v = ((const float4*)in)[i];
        ushort4 o; o.x = f2h(v.x); o.y = f2h(v.y); o.z = f2h(v.z); o.w = f2h(v.w);
        ((ushort4*)out)[i] = o;
    }
}

// ---------------------------------------------------------------------------
// Weight prep: f32 W[K][M] -> f16 in LDS-tile order:
// dst = mat + kt*(M*32) + (n>>7)*4096 + p*8 + (k&7),
// p = ((n&127)>>4)*64 + ((k>>3)&3)*16 + (n&15).  (tile = 8KB, DMA-linear)
// ---------------------------------------------------------------------------
__global__ void prep_w(const float* __restrict__ s0, const float* __restrict__ s1,
                       const float* __restrict__ s2, const float* __restrict__ s3,
                       const float* __restrict__ s4, const float* __restrict__ s5,
                       const float* __restrict__ s6, const float* __restrict__ s7,
                       ushort_t* __restrict__ hi)
{
    long gid = (long)blockIdx.x * 256 + threadIdx.x;
    const float* src; int K, M; long base, loc;
    if      (gid < 524288)  { src=s0; K=256; M=512; base=0;       loc=gid; }
    else if (gid < 1048576) { src=s1; K=512; M=256; base=524288;  loc=gid-524288; }
    else if (gid < 1572864) { src=s2; K=256; M=512; base=1048576; loc=gid-1048576; }
    else if (gid < 2097152) { src=s3; K=512; M=256; base=1572864; loc=gid-1572864; }
    else if (gid < 2359296) { src=s4; K=256; M=256; base=2097152; loc=gid-2097152; }
    else if (gid < 2621440) { src=s5; K=256; M=256; base=2359296; loc=gid-2359296; }
    else if (gid < 2637824) { src=s6; K=64;  M=256; base=2621440; loc=gid-2621440; }
    else if (gid < 2646016) { src=s7; K=32;  M=256; base=2637824; loc=gid-2637824; }
    else return;
    long msz = (long)K * M;
    int  mat = (int)(loc / msz); long rem = loc - (long)mat * msz;
    int  k = (int)(rem / M);     int  n = (int)(rem - (long)k * M);
    int nl = n & 127, g = (k >> 3) & 3;
    long p = (long)((nl >> 4) * 64 + g * 16 + (nl & 15));
    long dst = base + (long)mat * msz + (long)(k >> 5) * ((long)M << 5)
             + ((long)(n >> 7) << 12) + (p << 3) + (k & 7);
    hi[dst] = f2h(src[loc]);
}

// ---------------------------------------------------------------------------
// MFMA f16 GEMM, 2-phase double-buffered staging (stage(next) || compute(cur)).
// ---------------------------------------------------------------------------
template<int RELU>
__global__ __launch_bounds__(256)
void mfma_gemm(PanelsIn Ap, int astride, const ushort_t* __restrict__ Wh,
               const float* __restrict__ bias,
               PanelsOut Cp, int cstride, const float* __restrict__ Aff,
               float* __restrict__ cstatR, int N, int K, int M)
{
    __shared__ ushort_t Asm[8192];   // 2 x 8KB A tiles
    __shared__ ushort_t Bhs[8192];   // 2 x 8KB W tiles
    __shared__ ushort_t AffS[1024];  // f16 sc[K] | sb[K] at +512
    const int tid = threadIdx.x;
    const int nwg = gridDim.x * gridDim.y;
    const int bid = blockIdx.y * gridDim.x + blockIdx.x;
    const int cpx = nwg >> 3;
    const int swz = (bid & 7) * cpx + (bid >> 3);
    const int bx = swz % gridDim.x, by = swz / gridDim.x;
    const int brow = by * 128, bcol = bx * 128;
    const int wid = tid >> 6, lane = tid & 63;
    const int wm = wid >> 1, wn = wid & 1;
    const int lg = lane >> 4, lr = lane & 15;

    if (Aff) {
        for (int c = tid; c < K; c += 256) {
            AffS[c]       = f2h(Aff[c]);
            AffS[512 + c] = f2h(Aff[K + c]);
        }
    }

    const int mA = lane & 15;
    const int gA = (lane >> 4) & 3;

    auto stage = [&](int kt, int b) {
        const ushort_t* pa = Ap.p[kt >> 2];
        const ushort_t* ga = pa + (long)(brow + wid * 16 + mA) * astride
                                + ((kt & 3) << 5) + gA * 8;
        load_lds16(ga, Asm + b * 4096 + wid * 512);
        load_lds16(ga + (long)64 * astride, Asm + b * 4096 + 2048 + wid * 512);
        const ushort_t* gb = Wh + (size_t)kt * ((size_t)M << 5)
                                + ((size_t)bcol << 5) + (wid * 64 + lane) * 8;
        load_lds16(gb, Bhs + b * 4096 + wid * 512);
        load_lds16(gb + 2048, Bhs + b * 4096 + 2048 + wid * 512);
    };

    floatx4 acc[4][4];
    #pragma unroll
    for (int i = 0; i < 4; ++i)
        #pragma unroll
        for (int j = 0; j < 4; ++j) acc[i][j] = (floatx4){0.f, 0.f, 0.f, 0.f};

    const int nkt = K >> 5;
    stage(0, 0);
    __syncthreads();
    for (int kt = 0; kt < nkt; ++kt) {
        const int cur = kt & 1;
        if (kt + 1 < nkt) stage(kt + 1, cur ^ 1);
        const ushort_t* Ab = Asm + cur * 4096;
        const ushort_t* Bb = Bhs + cur * 4096;

        half8_t af[4], bh[4];
        #pragma unroll
        for (int i = 0; i < 4; ++i)
            af[i] = *(const half8_t*)(Ab + (((wm * 4 + i) * 64 + lg * 16 + lr) << 3));
        if (Aff) {
            half8_t scv = *(const half8_t*)(AffS + (kt << 5) + lg * 8);
            half8_t sbv = *(const half8_t*)(AffS + 512 + (kt << 5) + lg * 8);
            #pragma unroll
            for (int i = 0; i < 4; ++i) {
                half8_t z = af[i] * scv + sbv;
                #pragma unroll
                for (int e = 0; e < 8; ++e)
                    z[e] = z[e] > (_Float16)0 ? z[e] : (_Float16)0;
                af[i] = z;
            }
        }
        #pragma unroll
        for (int j = 0; j < 4; ++j)
            bh[j] = *(const half8_t*)(Bb + (((wn * 4 + j) * 64 + lg * 16 + lr) << 3));
        #pragma unroll
        for (int i = 0; i < 4; ++i)
            #pragma unroll
            for (int j = 0; j < 4; ++j)
                acc[i][j] = __builtin_amdgcn_mfma_f32_16x16x32_f16(af[i], bh[j], acc[i][j], 0, 0, 0);
        __syncthreads();
    }

    ushort_t* cb = Cp.p[bx];
    float csl[4], cql[4];
    #pragma unroll
    for (int j = 0; j < 4; ++j) { csl[j] = 0.f; cql[j] = 0.f; }
    #pragma unroll
    for (int j = 0; j < 4; ++j) {
        int lcol = wn * 64 + j * 16 + lr;
        float bia = bias[bcol + lcol];
        #pragma unroll
        for (int i = 0; i < 4; ++i) {
            #pragma unroll
            for (int r = 0; r < 4; ++r) {
                int row = brow + wm * 64 + i * 16 + (lg << 2) + r;
                float v = acc[i][j][r] + bia;
                if (RELU) v = fmaxf(v, 0.f);
                ushort_t uo = f2h(v);
                cb[(long)row * cstride + lcol] = uo;
                if (cstatR) {
                    float vq = h2f(uo);
                    csl[j] += vq; cql[j] = fmaf(vq, vq, cql[j]);
                }
            }
        }
    }
    if (cstatR) {
        __syncthreads();
        float* cs = (float*)Asm;
        float* cq = (float*)Bhs;
        if (tid < 128) { cs[tid] = 0.f; cq[tid] = 0.f; }
        __syncthreads();
        #pragma unroll
        for (int j = 0; j < 4; ++j) {
            int cl = wn * 64 + j * 16 + lr;
            atomicAdd(&cs[cl], csl[j]);
            atomicAdd(&cq[cl], cql[j]);
        }
        __syncthreads();
        if (tid < 128) {
            int rep = by & (NREP - 1);
            atomicAdd(&cstatR[(long)rep * 2 * M + bcol + tid], cs[tid]);
            atomicAdd(&cstatR[(long)rep * 2 * M + M + bcol + tid], cq[tid]);
        }
    }
}

// aff[c] = sa, aff[M+c] = sb from replicated stats + BN params
__global__ void finalize_aff(const float* __restrict__ cstatR, int M, float invN,
                             const float* __restrict__ g, const float* __restrict__ b,
                             float* __restrict__ aff)
{
    int c = blockIdx.x * blockDim.x + threadIdx.x;
    if (c >= M) return;
    float s = 0.f, q = 0.f;
    for (int r = 0; r < NREP; ++r) {
        s += cstatR[(long)r * 2 * M + c];
        q += cstatR[(long)r * 2 * M + M + c];
    }
    float m = s * invN, var = q * invN - m * m;
    float sa = rsqrtf(var + 1e-5f) * g[c];
    aff[c] = sa; aff[M + c] = b[c] - m * sa;
}

// ---------------------------------------------------------------------------
// CSR aggregation (one wave per node, grid-stride). selist[i] = {sid, eid}.
// ---------------------------------------------------------------------------
template<int EB>
__global__ __launch_bounds__(256)
void csr_agg(const ushort_t* __restrict__ in, ushort_t* __restrict__ out,
             const int* __restrict__ offs, const int2* __restrict__ selist,
             const float* __restrict__ eattr,
             const float* __restrict__ Wb, const float* __restrict__ bb,
             const float* __restrict__ eps_p, int n_nodes)
{
    __shared__ float Ws[EB ? 4096 : 1];
    __shared__ float bs[EB ? 256 : 1];
    if (EB) {
        for (int i = threadIdx.x; i < 4096; i += 256) Ws[i] = Wb[i];
        bs[threadIdx.x] = bb[threadIdx.x];
        __syncthreads();
    }
    float epsv = 1.f + eps_p[0];
    int lane = threadIdx.x & 63;
    int gw = (blockIdx.x * 256 + threadIdx.x) >> 6;
    int nw = (gridDim.x * 256) >> 6;
    for (int u = gw; u < n_nodes; u += nw) {
        const ushort_t* own = in + (long)u * 256;
        float acc[4];
        #pragma unroll
        for (int j = 0; j < 4; ++j) acc[j] = epsv * h2f(own[lane + 64 * j]);
        int s = offs[u], e = offs[u + 1];
        for (int i = s; i < e; ++i) {
            int2 se = selist[i];
            const ushort_t* row = in + (long)se.x * 256;
            if (EB) {
                float ev[16];
                const float4* ea = (const float4*)(eattr + (long)se.y * 16);
                float4 e0 = ea[0], e1 = ea[1], e2 = ea[2], e3 = ea[3];
                ev[0]=e0.x; ev[1]=e0.y; ev[2]=e0.z; ev[3]=e0.w;
                ev[4]=e1.x; ev[5]=e1.y; ev[6]=e1.z; ev[7]=e1.w;
                ev[8]=e2.x; ev[9]=e2.y; ev[10]=e2.z; ev[11]=e2.w;
                ev[12]=e3.x; ev[13]=e3.y; ev[14]=e3.z; ev[15]=e3.w;
                #pragma unroll
                for (int j = 0; j < 4; ++j) {
                    int c = lane + 64 * j;
                    float m = bs[c];
                    #pragma unroll
                    for (int k = 0; k < 16; ++k) m = fmaf(ev[k], Ws[k * 256 + c], m);
                    acc[j] += fmaxf(h2f(row[c]) + m, 0.f);
                }
            } else {
                #pragma unroll
                for (int j = 0; j < 4; ++j) acc[j] += h2f(row[lane + 64 * j]);
            }
        }
        ushort_t* o = out + (long)u * 256;
        #pragma unroll
        for (int j = 0; j < 4; ++j) o[lane + 64 * j] = f2h(acc[j]);
    }
}

// out[u] = relu(aff(raw[u])) + mean_{i in csr[u]} U[vlist[i]]   (256 ch)
// 256 threads / 2 nodes per block.
__global__ __launch_bounds__(256)
void csr_mean_aff(const ushort_t* __restrict__ raw, const ushort_t* __restrict__ U,
                  const int* __restrict__ vlist, const int* __restrict__ offs,
                  const float* __restrict__ Aff, ushort_t* __restrict__ outp,
                  int n_nodes)
{
    int u = blockIdx.x * 2 + (threadIdx.x >> 7);
    int t = threadIdx.x & 127;
    if (u >= n_nodes) return;
    int c0 = t * 2;
    float sa0 = Aff[c0], sa1 = Aff[c0 + 1], sb0 = Aff[256 + c0], sb1 = Aff[256 + c0 + 1];
    ushort2 b = *(const ushort2*)(raw + (long)u * 256 + c0);
    float x0 = fmaxf(h2f(b.x) * sa0 + sb0, 0.f);
    float x1 = fmaxf(h2f(b.y) * sa1 + sb1, 0.f);
    int s = offs[u], e = offs[u + 1];
    float a0 = 0.f, a1 = 0.f;
    for (int i = s; i < e; ++i) {
        long r = vlist[i];
        ushort2 v = *(const ushort2*)(U + r * 256 + c0);
        a0 += h2f(v.x); a1 += h2f(v.y);
    }
    if (e > s) { float inv = 1.f / (float)(e - s); x0 += a0 * inv; x1 += a1 * inv; }
    ushort2 o; o.x = f2h(x0); o.y = f2h(x1);
    *(ushort2*)(outp + (long)u * 256 + c0) = o;
}

// ---------------------------------------------------------------------------
// fp32 GEMM for readout (small). LDA=133: conflict-free A-tile writes.
// ---------------------------------------------------------------------------
template<int RELU, typename TC>
__global__ __launch_bounds__(256)
void gemm_k(const float* __restrict__ A, const float* __restrict__ W,
            const float* __restrict__ bias, TC* __restrict__ C,
            int N, int K, int M)
{
    const int BK = 16, LDA = 133;
    __shared__ float As[BK * LDA];
    __shared__ float Bs[BK * LDA];
    const int brow = blockIdx.y * 128;
    const int bcol = blockIdx.x * 128;
    const int tid  = threadIdx.x;
    const int tr = tid >> 4, tc = tid & 15;

    float acc[8][8];
    #pragma unroll
    for (int i = 0; i < 8; ++i)
        #pragma unroll
        for (int j = 0; j < 8; ++j) acc[i][j] = 0.f;

    for (int k0 = 0; k0 < K; k0 += BK) {
        #pragma unroll
        for (int u = 0; u < 8; ++u) {
            int idx = tid + u * 256;
            int m = idx >> 4, kk = idx & 15;
            As[kk * LDA + m] = A[(long)(brow + m) * K + k0 + kk];
        }
        #pragma unroll
        for (int u = 0; u < 8; ++u) {
            int idx = tid + u * 256;
            int kk = idx >> 7, n = idx & 127;
            int col = bcol + n;
            Bs[kk * LDA + n] = (col < M) ? W[(long)(k0 + kk) * M + col] : 0.f;
        }
        __syncthreads();
        #pragma unroll
        for (int kk = 0; kk < BK; ++kk) {
            float av[8], bv[8];
            float4 a0 = *(const float4*)&As[kk * LDA + tr * 8];
            float4 a1 = *(const float4*)&As[kk * LDA + tr * 8 + 4];
            float4 b0 = *(const float4*)&Bs[kk * LDA + tc * 8];
            float4 b1 = *(const float4*)&Bs[kk * LDA + tc * 8 + 4];
            av[0]=a0.x; av[1]=a0.y; av[2]=a0.z; av[3]=a0.w;
            av[4]=a1.x; av[5]=a1.y; av[6]=a1.z; av[7]=a1.w;
            bv[0]=b0.x; bv[1]=b0.y; bv[2]=b0.z; bv[3]=b0.w;
            bv[4]=b1.x; bv[5]=b1.y; bv[6]=b1.z; bv[7]=b1.w;
            #pragma unroll
            for (int i = 0; i < 8; ++i)
                #pragma unroll
                for (int j = 0; j < 8; ++j)
                    acc[i][j] = fmaf(av[i], bv[j], acc[i][j]);
        }
        __syncthreads();
    }
    #pragma unroll
    for (int i = 0; i < 8; ++i) {
        int row = brow + tr * 8 + i;
        #pragma unroll
        for (int j = 0; j < 8; ++j) {
            int col = bcol + tc * 8 + j;
            if (col < M) {
                float v = acc[i][j] + bias[col];
                if (RELU) v = fmaxf(v, 0.f);
                if constexpr (sizeof(TC) == 2) ((ushort_t*)C)[(long)row * M + col] = f2h(v);
                else                           ((float*)C)[(long)row * M + col] = v;
            }
        }
    }
}

__global__ void count_idx(const int* __restrict__ idx, int n, int* __restrict__ cnt)
{
    int i = blockIdx.x * blockDim.x + threadIdx.x;
    if (i < n) atomicAdd(&cnt[idx[i]], 1);
}

// ---- parallel exclusive scan (3 phases) ----
__global__ __launch_bounds__(256)
void scan_p1(const int* __restrict__ cnt, int n, int* __restrict__ partials)
{
    __shared__ int sd[256];
    int i = blockIdx.x * 256 + threadIdx.x;
    sd[threadIdx.x] = (i < n) ? cnt[i] : 0;
    __syncthreads();
    #pragma unroll
    for (int s = 128; s > 0; s >>= 1) {
        if (threadIdx.x < s) sd[threadIdx.x] += sd[threadIdx.x + s];
        __syncthreads();
    }
    if (threadIdx.x == 0) partials[blockIdx.x] = sd[0];
}

__global__ __launch_bounds__(1024)
void scan_p2(int* __restrict__ partials, int nb, int* __restrict__ off, int n)
{
    __shared__ int sd[1024];
    int t = threadIdx.x;
    int v = (t < nb) ? partials[t] : 0;
    sd[t] = v;
    __syncthreads();
    for (int d = 1; d < 1024; d <<= 1) {
        int x = (t >= d) ? sd[t - d] : 0;
        __syncthreads();
        sd[t] += x;
        __syncthreads();
    }
    if (t < nb) partials[t] = sd[t] - v;
    if (t == 1023) off[n] = sd[nb - 1];
}

__global__ __launch_bounds__(256)
void scan_p3(const int* __restrict__ cnt, int n, const int* __restrict__ partials,
             int* __restrict__ off, int* __restrict__ cursor)
{
    __shared__ int sd[256];
    int i = blockIdx.x * 256 + threadIdx.x;
    int v = (i < n) ? cnt[i] : 0;
    sd[threadIdx.x] = v;
    __syncthreads();
    for (int d = 1; d < 256; d <<= 1) {
        int x = (threadIdx.x >= d) ? sd[threadIdx.x - d] : 0;
        __syncthreads();
        sd[threadIdx.x] += x;
        __syncthreads();
    }
    if (i < n) {
        int e = partials[blockIdx.x] + sd[threadIdx.x] - v;
        off[i] = e; cursor[i] = e;
    }
}

// pair fill: elist2[p] = {other[i], i}
__global__ void csr_fill_pair(const int* __restrict__ idx, const int* __restrict__ other,
                              int n, int* __restrict__ cursor, int2* __restrict__ elist2)
{
    int i = blockIdx.x * blockDim.x + threadIdx.x;
    if (i < n) { int p = atomicAdd(&cursor[idx[i]], 1); elist2[p] = make_int2(other[i], i); }
}

// value fill: vlist[p] = other[i]
__global__ void csr_fill_val(const int* __restrict__ idx, const int* __restrict__ other,
                             int n, int* __restrict__ cursor, int* __restrict__ vlist)
{
    int i = blockIdx.x * blockDim.x + threadIdx.x;
    if (i < n) { int p = atomicAdd(&cursor[idx[i]], 1); vlist[p] = other[i]; }
}

__global__ __launch_bounds__(256)
void seg_pool(const ushort_t* __restrict__ X, const int* __restrict__ bidx,
              int nrows, float* __restrict__ pooled)
{
    int b = blockIdx.x, t = threadIdx.x;
    int lo = 0, hi = nrows;
    while (lo < hi) { int mid = (lo + hi) >> 1; if (bidx[mid] < b) lo = mid + 1; else hi = mid; }
    int s = lo; hi = nrows;
    while (lo < hi) { int mid = (lo + hi) >> 1; if (bidx[mid] < b + 1) lo = mid + 1; else hi = mid; }
    int e = lo;
    float acc = 0.f;
    for (int r = s; r < e; ++r) acc += h2f(X[(long)r * 256 + t]);
    pooled[(long)b * 256 + t] = acc / fmaxf((float)(e - s), 1.f);
}

__global__ void vadd(float* __restrict__ out, const float* __restrict__ in, long n4)
{
    long t = (long)blockIdx.x * blockDim.x + threadIdx.x;
    if (t >= n4) return;
    float4 a = ((float4*)out)[t];
    float4 b = ((const float4*)in)[t];
    a.x += b.x; a.y += b.y; a.z += b.z; a.w += b.w;
    ((float4*)out)[t] = a;
}

// ---------------------------------------------------------------------------
extern "C" void kernel_launch(void* const* d_in, const int* in_sizes, int n_in,
                              void* d_out, int out_size, void* d_ws, size_t ws_size,
                              hipStream_t stream)
{
    (void)in_sizes; (void)n_in;
    const float* x          = (const float*)d_in[0];
    const float* fragments  = (const float*)d_in[1];
    const float* edge_attr  = (const float*)d_in[2];
    const float* atom_enc_W = (const float*)d_in[3];
    const float* atom_enc_b = (const float*)d_in[4];
    const float* frag_enc_W = (const float*)d_in[5];
    const float* frag_enc_b = (const float*)d_in[6];
    const float* bond_W     = (const float*)d_in[7];
    const float* bond_b     = (const float*)d_in[8];
    const float* gine_eps   = (const float*)d_in[9];
    const float* gine_W1    = (const float*)d_in[10];
    const float* gine_b1    = (const float*)d_in[11];
    const float* gine_bn_g  = (const float*)d_in[12];
    const float* gine_bn_b  = (const float*)d_in[13];
    const float* gine_W2    = (const float*)d_in[14];
    const float* gine_b2    = (const float*)d_in[15];
    const float* atom_bn_g  = (const float*)d_in[16];
    const float* atom_bn_b  = (const float*)d_in[17];
    const float* gin_eps    = (const float*)d_in[18];
    const float* gin_W1     = (const float*)d_in[19];
    const float* gin_b1     = (const float*)d_in[20];
    const float* gin_bn_g   = (const float*)d_in[21];
    const float* gin_bn_b   = (const float*)d_in[22];
    const float* gin_W2     = (const float*)d_in[23];
    const float* gin_b2     = (const float*)d_in[24];
    const float* frag_bn_g  = (const float*)d_in[25];
    const float* frag_bn_b  = (const float*)d_in[26];
    const float* a2f_W      = (const float*)d_in[27];
    const float* a2f_b      = (const float*)d_in[28];
    const float* f2a_W      = (const float*)d_in[29];
    const float* f2a_b      = (const float*)d_in[30];
    const float* fo_W1      = (const float*)d_in[31];
    const float* fo_b1      = (const float*)d_in[32];
    const float* fo_W2      = (const float*)d_in[33];
    const float* fo_b2      = (const float*)d_in[34];
    const float* ao_W1      = (const float*)d_in[35];
    const float* ao_b1      = (const float*)d_in[36];
    const float* ao_W2      = (const float*)d_in[37];
    const float* ao_b2      = (const float*)d_in[38];
    const float* out_W1     = (const float*)d_in[39];
    const float* out_b1     = (const float*)d_in[40];
    const float* out_W2     = (const float*)d_in[41];
    const float* out_b2     = (const float*)d_in[42];
    const int* edge_index   = (const int*)d_in[43];
    const int* fedge_index  = (const int*)d_in[44];
    const int* batch        = (const int*)d_in[45];
    const int* fbatch       = (const int*)d_in[46];
    const int* mem_atom     = (const int*)d_in[47];
    const int* mem_frag     = (const int*)d_in[48];

    const int* src  = edge_index;
    const int* dst  = edge_index + N_EDGE;
    const int* fsrc = fedge_index;
    const int* fdst = fedge_index + N_FEDGE;

    // ---- arena ----
    const size_t WPN = 2646016;
    size_t off = 0;
    auto take = [&](size_t b) -> size_t { size_t p = off; off = (off + b + 255) & ~(size_t)255; return p; };
    size_t o_big   = take((size_t)N_ATOM * 512 * 2);     // 134 MB
    size_t o_a     = take((size_t)N_ATOM * H * 2);       // 67 MB
    size_t o_f     = take((size_t)N_FRAG * H * 2);
    size_t o_f2    = take((size_t)N_FRAG * H * 2);
    size_t o_offea = take((size_t)(N_ATOM + 1) * 4);
    size_t o_elea  = take((size_t)N_EDGE * 8);           // int2
    size_t o_offef = take((size_t)(N_FRAG + 1) * 4);
    size_t o_elef  = take((size_t)N_FEDGE * 8);          // int2
    size_t o_offma = take((size_t)(N_ATOM + 1) * 4);
    size_t o_elma  = take((size_t)N_MEM * 4);
    size_t o_offmf = take((size_t)(N_FRAG + 1) * 4);
    size_t o_elmf  = take((size_t)N_MEM * 4);
    size_t o_cnta  = take((size_t)N_ATOM * 4);
    size_t o_cntf  = take((size_t)N_FRAG * 4);
    size_t o_part  = take(1024 * 4);
    size_t o_stats = take((size_t)NREP * 3072 * 4);
    size_t o_aff   = take(3072 * 4);
    size_t o_hi    = take(WPN * 2);
    size_t need = off;

    if (need > ws_size) {
        fill_const<<<64, 256, 0, stream>>>((float*)d_out, out_size,
                                           (float)((double)ws_size / 1024.0));
        return;
    }
    char* base = (char*)d_ws;
    char*     big     = base + o_big;
    ushort_t* a       = (ushort_t*)(base + o_a);
    ushort_t* f       = (ushort_t*)(base + o_f);
    ushort_t* f2      = (ushort_t*)(base + o_f2);
    int*  off_ea = (int*)(base + o_offea);
    int2* el_ea  = (int2*)(base + o_elea);
    int*  off_ef = (int*)(base + o_offef);
    int2* el_ef  = (int2*)(base + o_elef);
    int*  off_ma = (int*)(base + o_offma);
    int*  el_ma  = (int*)(base + o_elma);
    int*  off_mf = (int*)(base + o_offmf);
    int*  el_mf  = (int*)(base + o_elmf);
    int*  cnt_a  = (int*)(base + o_cnta);
    int*  cnt_f  = (int*)(base + o_cntf);
    int*  parts  = (int*)(base + o_part);
    float* statsR = (float*)(base + o_stats);
    float* affs   = (float*)(base + o_aff);
    ushort_t* Wp_hi = (ushort_t*)(base + o_hi);

    float* cst1a = statsR;
    float* cst2a = statsR + (size_t)NREP * 1024;
    float* cst1f = statsR + (size_t)NREP * 1536;
    float* cst2f = statsR + (size_t)NREP * 2560;
    float* aff1_a = affs;
    float* aff2_a = affs + 1024;
    float* aff1_f = affs + 1536;
    float* aff2_f = affs + 2560;

    ushort_t* big_u = (ushort_t*)big;
    const size_t HALF_U = (size_t)N_ATOM * 256;
    ushort_t* ha  = big_u + HALF_U;
    const size_t PAN_A = (size_t)N_ATOM * 128;
    const size_t PAN_F = (size_t)N_FRAG * 128;
    ushort_t* Ua = big_u;
    float* pooled_f = (float*)big;
    float* pooled_a = (float*)(big + (size_t)8 * 1024 * 1024);
    float* tmp      = (float*)(big + (size_t)16 * 1024 * 1024);
    ushort_t* xh = big_u;
    ushort_t* fh = big_u + (size_t)N_ATOM * 64;

    const long WG0 = 0, WG1 = 524288, WG2 = 1048576, WG3 = 1572864,
               WG4 = 2097152, WG5 = 2359296, WG6 = 2621440, WG7 = 2637824;

    auto build_off = [&](const int* idx, int n_edges, int n_nodes, int* cnt, int* offs) {
        hipMemsetAsync(cnt, 0, (size_t)n_nodes * 4, stream);
        count_idx<<<CDIV(n_edges,256),256,0,stream>>>(idx, n_edges, cnt);
        int nb = CDIV(n_nodes, 256);
        scan_p1<<<nb, 256, 0, stream>>>(cnt, n_nodes, parts);
        scan_p2<<<1, 1024, 0, stream>>>(parts, nb, offs, n_nodes);
        scan_p3<<<nb, 256, 0, stream>>>(cnt, n_nodes, parts, offs, cnt);
    };

    // ---- weight prep + CSR builds ----
    prep_w<<<CDIV((long)WPN, 256), 256, 0, stream>>>(gine_W1, gine_W2, gin_W1, gin_W2,
                                                     a2f_W, f2a_W, atom_enc_W, frag_enc_W,
                                                     Wp_hi);
    build_off(dst, N_EDGE, N_ATOM, cnt_a, off_ea);
    csr_fill_pair<<<CDIV(N_EDGE,256),256,0,stream>>>(dst, src, N_EDGE, cnt_a, el_ea);
    build_off(fdst, N_FEDGE, N_FRAG, cnt_f, off_ef);
    csr_fill_pair<<<CDIV(N_FEDGE,256),256,0,stream>>>(fdst, fsrc, N_FEDGE, cnt_f, el_ef);
    build_off(mem_atom, N_MEM, N_ATOM, cnt_a, off_ma);
    csr_fill_val<<<CDIV(N_MEM,256),256,0,stream>>>(mem_atom, mem_frag, N_MEM, cnt_a, el_ma);
    build_off(mem_frag, N_MEM, N_FRAG, cnt_f, off_mf);
    csr_fill_val<<<CDIV(N_MEM,256),256,0,stream>>>(mem_frag, mem_atom, N_MEM, cnt_f, el_mf);

    // ---- encoders via MFMA (f16 inputs staged in big) ----
    conv_f2h<<<2048, 256, 0, stream>>>(x, xh, (long)N_ATOM * 64);
    conv_f2h<<<512, 256, 0, stream>>>(fragments, fh, (long)N_FRAG * 32);
    {
        PanelsIn Ein; PanelsOut Eout;
        for (int i = 0; i < 4; ++i) Ein.p[i] = xh;
        Eout.p[0] = a; Eout.p[1] = a + 128; Eout.p[2] = a; Eout.p[3] = a;
        mfma_gemm<0><<<dim3(2, N_ATOM/128), 256, 0, stream>>>(
            Ein, 64, Wp_hi + WG6, atom_enc_b, Eout, 256, nullptr, nullptr,
            N_ATOM, 64, 256);
        PanelsIn Fin; PanelsOut Fout;
        for (int i = 0; i < 4; ++i) Fin.p[i] = fh;
        Fout.p[0] = f; Fout.p[1] = f + 128; Fout.p[2] = f; Fout.p[3] = f;
        mfma_gemm<0><<<dim3(2, N_FRAG/128), 256, 0, stream>>>(
            Fin, 32, Wp_hi + WG7, frag_enc_b, Fout, 256, nullptr, nullptr,
            N_FRAG, 32, 256);
    }

    const float invNA = 1.f / N_ATOM, invNF = 1.f / N_FRAG;

    for (int l = 0; l < 4; ++l) {
        hipMemsetAsync(statsR, 0, (size_t)NREP * 3072 * 4, stream);

        // ===== atoms: GINE + MLP =====
        csr_agg<1><<<2048, 256, 0, stream>>>(a, ha, off_ea, el_ea, edge_attr,
            bond_W + (long)l*16*H, bond_b + l*H, gine_eps + l, N_ATOM);

        PanelsIn A1in; PanelsOut A1out;
        for (int i = 0; i < 4; ++i) A1in.p[i] = ha + i * 128;
        A1out.p[0] = a;          A1out.p[1] = a + PAN_A;
        A1out.p[2] = big_u;      A1out.p[3] = big_u + PAN_A;
        mfma_gemm<0><<<dim3(4, N_ATOM/128), 256, 0, stream>>>(
            A1in, 256, Wp_hi + WG0 + (long)l*131072,
            gine_b1 + l*512, A1out, 128, nullptr, cst1a, N_ATOM, 256, 512);
        finalize_aff<<<2, 256, 0, stream>>>(cst1a, 512, invNA,
            gine_bn_g + l*512, gine_bn_b + l*512, aff1_a);

        PanelsIn A2in; PanelsOut A2out;
        A2in.p[0] = a;       A2in.p[1] = a + PAN_A;
        A2in.p[2] = big_u;   A2in.p[3] = big_u + PAN_A;
        A2out.p[0] = ha; A2out.p[1] = ha + 128; A2out.p[2] = ha; A2out.p[3] = ha;
        mfma_gemm<0><<<dim3(2, N_ATOM/128), 256, 0, stream>>>(
            A2in, 128, Wp_hi + WG1 + (long)l*131072,
            gine_b2 + l*H, A2out, 256, aff1_a, cst2a, N_ATOM, 512, 256);
        finalize_aff<<<1, 256, 0, stream>>>(cst2a, 256, invNA,
            atom_bn_g + l*H, atom_bn_b + l*H, aff2_a);

        // ===== fragments: GIN + MLP =====
        csr_agg<0><<<512, 256, 0, stream>>>(f, f2, off_ef, el_ef, nullptr,
            nullptr, nullptr, gin_eps + l, N_FRAG);

        PanelsIn F1in; PanelsOut F1out;
        for (int i = 0; i < 4; ++i) F1in.p[i] = f2 + i * 128;
        for (int i = 0; i < 4; ++i) F1out.p[i] = big_u + i * PAN_F;
        mfma_gemm<0><<<dim3(4, N_FRAG/128), 256, 0, stream>>>(
            F1in, 256, Wp_hi + WG2 + (long)l*131072,
            gin_b1 + l*512, F1out, 128, nullptr, cst1f, N_FRAG, 256, 512);
        finalize_aff<<<2, 256, 0, stream>>>(cst1f, 512, invNF,
            gin_bn_g + l*512, gin_bn_b + l*512, aff1_f);

        PanelsIn F2in; PanelsOut F2out;
        for (int i = 0; i < 4; ++i) F2in.p[i] = big_u + i * PAN_F;
        F2out.p[0] = f2; F2out.p[1] = f2 + 128; F2out.p[2] = f2; F2out.p[3] = f2;
        mfma_gemm<0><<<dim3(2, N_FRAG/128), 256, 0, stream>>>(
            F2in, 128, Wp_hi + WG3 + (long)l*131072,
            gin_b2 + l*H, F2out, 256, aff1_f, cst2f, N_FRAG, 512, 256);
        finalize_aff<<<1, 256, 0, stream>>>(cst2f, 256, invNF,
            frag_bn_g + l*H, frag_bn_b + l*H, aff2_f);

        // ===== inter MP =====
        PanelsIn UAin; PanelsOut UAout;
        for (int i = 0; i < 4; ++i) UAin.p[i] = ha + i * 128;
        UAout.p[0] = Ua; UAout.p[1] = Ua + 128; UAout.p[2] = Ua; UAout.p[3] = Ua;
        mfma_gemm<1><<<dim3(2, N_ATOM/128), 256, 0, stream>>>(
            UAin, 256, Wp_hi + WG4 + (long)l*65536,
            a2f_b + l*H, UAout, 256, aff2_a, nullptr, N_ATOM, 256, 256);
        csr_mean_aff<<<N_FRAG/2, 256, 0, stream>>>(f2, Ua, el_mf, off_mf,
                                                   aff2_f, f, N_FRAG);
        PanelsIn UFin; PanelsOut UFout;
        for (int i = 0; i < 4; ++i) UFin.p[i] = f + i * 128;
        UFout.p[0] = f2; UFout.p[1] = f2 + 128; UFout.p[2] = f2; UFout.p[3] = f2;
        mfma_gemm<1><<<dim3(2, N_FRAG/128), 256, 0, stream>>>(
            UFin, 256, Wp_hi + WG5 + (long)l*65536,
            f2a_b + l*H, UFout, 256, nullptr, nullptr, N_FRAG, 256, 256);
        csr_mean_aff<<<N_ATOM/2, 256, 0, stream>>>(ha, f2, el_ma, off_ma,
                                                   aff2_a, a, N_ATOM);
    }

    // ===== readout =====
    seg_pool<<<BATCH, 256, 0, stream>>>(f, fbatch, N_FRAG, pooled_f);
    gemm_k<1,float><<<dim3(2, BATCH/128), 256, 0, stream>>>(
        pooled_f, fo_W1, fo_b1, tmp, BATCH, H, H);
    gemm_k<1,float><<<dim3(2, BATCH/128), 256, 0, stream>>>(
        tmp, fo_W2, fo_b2, pooled_f, BATCH, H, H);

    seg_pool<<<BATCH, 256, 0, stream>>>(a, batch, N_ATOM, pooled_a);
    gemm_k<1,float><<<dim3(2, BATCH/128), 256, 0, stream>>>(
        pooled_a, ao_W1, ao_b1, tmp, BATCH, H, H);
    gemm_k<1,float><<<dim3(2, BATCH/128), 256, 0, stream>>>(
        tmp, ao_W2, ao_b2, pooled_a, BATCH, H, H);

    vadd<<<(int)CDIV((long)BATCH*H/4,256), 256, 0, stream>>>(
        pooled_a, pooled_f, (long)BATCH * H / 4);
    gemm_k<1,float><<<dim3(2, BATCH/128), 256, 0, stream>>>(
        pooled_a, out_W1, out_b1, tmp, BATCH, H, H);
    gemm_k<0,float><<<dim3(1, BATCH/128), 256, 0, stream>>>(
        tmp, out_W2, out_b2, (float*)d_out, BATCH, H, 1);
}

// Round 15
// 3182.966 us; speedup vs baseline: 1.0342x; 1.0342x over previous
//
#include <hip/hip_runtime.h>

#define CDIV(a,b) (((a)+(b)-1)/(b))

static const int N_ATOM = 131072, N_FRAG = 32768, N_EDGE = 262144,
                 N_FEDGE = 65536, N_MEM = 196608, BATCH = 4096, H = 256;
static const int NREP = 16;   // stat atomic replicas

typedef unsigned short ushort_t;
typedef _Float16 half8_t __attribute__((ext_vector_type(8)));
typedef float    floatx4 __attribute__((ext_vector_type(4)));

struct PanelsIn  { const ushort_t* p[4]; };
struct PanelsOut { ushort_t* p[4]; };

__device__ __forceinline__ float h2f(ushort_t u) {
    _Float16 h; __builtin_memcpy(&h, &u, 2); return (float)h;
}
__device__ __forceinline__ ushort_t f2h(float f) {
    _Float16 h = (_Float16)f; ushort_t u; __builtin_memcpy(&u, &h, 2); return u;
}

// async global->LDS, 16B per lane. lds base must be wave-uniform; HW adds lane*16.
__device__ __forceinline__ void load_lds16(const ushort_t* g, ushort_t* l) {
    __builtin_amdgcn_global_load_lds(
        (const __attribute__((address_space(1))) unsigned int*)g,
        (__attribute__((address_space(3))) unsigned int*)l, 16, 0, 0);
}

__global__ void fill_const(float* p, long n, float v) {
    long t = (long)blockIdx.x * blockDim.x + threadIdx.x;
    long stride = (long)gridDim.x * blockDim.x;
    for (; t < n; t += stride) p[t] = v;
}

// f32 -> f16 bulk convert (n % 4 == 0)
__global__ void conv_f2h(const float* __restrict__ in, ushort_t* __restrict__ out, long n)
{
    long t = (long)blockIdx.x * 256 + threadIdx.x;
    long stride = (long)gridDim.x * 256;
    for (long i = t; i < n / 4; i += stride) {
        float4 v = ((const float4*)in)[i];
        ushort4 o; o.x = f2h(v.x); o.y = f2h(v.y); o.z = f2h(v.z); o.w = f2h(v.w);
        ((ushort4*)out)[i] = o;
    }
}

// ---------------------------------------------------------------------------
// Weight prep: f32 W[K][M] -> f16 in LDS-tile order.
// ---------------------------------------------------------------------------
__global__ void prep_w(const float* __restrict__ s0, const float* __restrict__ s1,
                       const float* __restrict__ s2, const float* __restrict__ s3,
                       const float* __restrict__ s4, const float* __restrict__ s5,
                       const float* __restrict__ s6, const float* __restrict__ s7,
                       ushort_t* __restrict__ hi)
{
    long gid = (long)blockIdx.x * 256 + threadIdx.x;
    const float* src; int K, M; long base, loc;
    if      (gid < 524288)  { src=s0; K=256; M=512; base=0;       loc=gid; }
    else if (gid < 1048576) { src=s1; K=512; M=256; base=524288;  loc=gid-524288; }
    else if (gid < 1572864) { src=s2; K=256; M=512; base=1048576; loc=gid-1048576; }
    else if (gid < 2097152) { src=s3; K=512; M=256; base=1572864; loc=gid-1572864; }
    else if (gid < 2359296) { src=s4; K=256; M=256; base=2097152; loc=gid-2097152; }
    else if (gid < 2621440) { src=s5; K=256; M=256; base=2359296; loc=gid-2359296; }
    else if (gid < 2637824) { src=s6; K=64;  M=256; base=2621440; loc=gid-2621440; }
    else if (gid < 2646016) { src=s7; K=32;  M=256; base=2637824; loc=gid-2637824; }
    else return;
    long msz = (long)K * M;
    int  mat = (int)(loc / msz); long rem = loc - (long)mat * msz;
    int  k = (int)(rem / M);     int  n = (int)(rem - (long)k * M);
    int nl = n & 127, g = (k >> 3) & 3;
    long p = (long)((nl >> 4) * 64 + g * 16 + (nl & 15));
    long dst = base + (long)mat * msz + (long)(k >> 5) * ((long)M << 5)
             + ((long)(n >> 7) << 12) + (p << 3) + (k & 7);
    hi[dst] = f2h(src[loc]);
}

// ---------------------------------------------------------------------------
// MFMA f16 GEMM, 2-phase double-buffered staging (stage(next) || compute(cur)).
// ---------------------------------------------------------------------------
template<int RELU>
__global__ __launch_bounds__(256)
void mfma_gemm(PanelsIn Ap, int astride, const ushort_t* __restrict__ Wh,
               const float* __restrict__ bias,
               PanelsOut Cp, int cstride, const float* __restrict__ Aff,
               float* __restrict__ cstatR, int N, int K, int M)
{
    __shared__ ushort_t Asm[8192];   // 2 x 8KB A tiles
    __shared__ ushort_t Bhs[8192];   // 2 x 8KB W tiles
    __shared__ ushort_t AffS[1024];  // f16 sc[K] | sb[K] at +512
    const int tid = threadIdx.x;
    const int nwg = gridDim.x * gridDim.y;
    const int bid = blockIdx.y * gridDim.x + blockIdx.x;
    const int cpx = nwg >> 3;
    const int swz = (bid & 7) * cpx + (bid >> 3);
    const int bx = swz % gridDim.x, by = swz / gridDim.x;
    const int brow = by * 128, bcol = bx * 128;
    const int wid = tid >> 6, lane = tid & 63;
    const int wm = wid >> 1, wn = wid & 1;
    const int lg = lane >> 4, lr = lane & 15;

    if (Aff) {
        for (int c = tid; c < K; c += 256) {
            AffS[c]       = f2h(Aff[c]);
            AffS[512 + c] = f2h(Aff[K + c]);
        }
    }

    const int mA = lane & 15;
    const int gA = (lane >> 4) & 3;

    auto stage = [&](int kt, int b) {
        const ushort_t* pa = Ap.p[kt >> 2];
        const ushort_t* ga = pa + (long)(brow + wid * 16 + mA) * astride
                                + ((kt & 3) << 5) + gA * 8;
        load_lds16(ga, Asm + b * 4096 + wid * 512);
        load_lds16(ga + (long)64 * astride, Asm + b * 4096 + 2048 + wid * 512);
        const ushort_t* gb = Wh + (size_t)kt * ((size_t)M << 5)
                                + ((size_t)bcol << 5) + (wid * 64 + lane) * 8;
        load_lds16(gb, Bhs + b * 4096 + wid * 512);
        load_lds16(gb + 2048, Bhs + b * 4096 + 2048 + wid * 512);
    };

    floatx4 acc[4][4];
    #pragma unroll
    for (int i = 0; i < 4; ++i)
        #pragma unroll
        for (int j = 0; j < 4; ++j) acc[i][j] = (floatx4){0.f, 0.f, 0.f, 0.f};

    const int nkt = K >> 5;
    stage(0, 0);
    __syncthreads();
    for (int kt = 0; kt < nkt; ++kt) {
        const int cur = kt & 1;
        if (kt + 1 < nkt) stage(kt + 1, cur ^ 1);
        const ushort_t* Ab = Asm + cur * 4096;
        const ushort_t* Bb = Bhs + cur * 4096;

        half8_t af[4], bh[4];
        #pragma unroll
        for (int i = 0; i < 4; ++i)
            af[i] = *(const half8_t*)(Ab + (((wm * 4 + i) * 64 + lg * 16 + lr) << 3));
        if (Aff) {
            half8_t scv = *(const half8_t*)(AffS + (kt << 5) + lg * 8);
            half8_t sbv = *(const half8_t*)(AffS + 512 + (kt << 5) + lg * 8);
            #pragma unroll
            for (int i = 0; i < 4; ++i) {
                half8_t z = af[i] * scv + sbv;
                #pragma unroll
                for (int e = 0; e < 8; ++e)
                    z[e] = z[e] > (_Float16)0 ? z[e] : (_Float16)0;
                af[i] = z;
            }
        }
        #pragma unroll
        for (int j = 0; j < 4; ++j)
            bh[j] = *(const half8_t*)(Bb + (((wn * 4 + j) * 64 + lg * 16 + lr) << 3));
        #pragma unroll
        for (int i = 0; i < 4; ++i)
            #pragma unroll
            for (int j = 0; j < 4; ++j)
                acc[i][j] = __builtin_amdgcn_mfma_f32_16x16x32_f16(af[i], bh[j], acc[i][j], 0, 0, 0);
        __syncthreads();
    }

    ushort_t* cb = Cp.p[bx];
    float csl[4], cql[4];
    #pragma unroll
    for (int j = 0; j < 4; ++j) { csl[j] = 0.f; cql[j] = 0.f; }
    #pragma unroll
    for (int j = 0; j < 4; ++j) {
        int lcol = wn * 64 + j * 16 + lr;
        float bia = bias[bcol + lcol];
        #pragma unroll
        for (int i = 0; i < 4; ++i) {
            #pragma unroll
            for (int r = 0; r < 4; ++r) {
                int row = brow + wm * 64 + i * 16 + (lg << 2) + r;
                float v = acc[i][j][r] + bia;
                if (RELU) v = fmaxf(v, 0.f);
                ushort_t uo = f2h(v);
                cb[(long)row * cstride + lcol] = uo;
                if (cstatR) {
                    float vq = h2f(uo);
                    csl[j] += vq; cql[j] = fmaf(vq, vq, cql[j]);
                }
            }
        }
    }
    if (cstatR) {
        __syncthreads();
        float* cs = (float*)Asm;
        float* cq = (float*)Bhs;
        if (tid < 128) { cs[tid] = 0.f; cq[tid] = 0.f; }
        __syncthreads();
        #pragma unroll
        for (int j = 0; j < 4; ++j) {
            int cl = wn * 64 + j * 16 + lr;
            atomicAdd(&cs[cl], csl[j]);
            atomicAdd(&cq[cl], cql[j]);
        }
        __syncthreads();
        if (tid < 128) {
            int rep = by & (NREP - 1);
            atomicAdd(&cstatR[(long)rep * 2 * M + bcol + tid], cs[tid]);
            atomicAdd(&cstatR[(long)rep * 2 * M + M + bcol + tid], cq[tid]);
        }
    }
}

// aff[c] = sa, aff[M+c] = sb from replicated stats + BN params
__global__ void finalize_aff(const float* __restrict__ cstatR, int M, float invN,
                             const float* __restrict__ g, const float* __restrict__ b,
                             float* __restrict__ aff)
{
    int c = blockIdx.x * blockDim.x + threadIdx.x;
    if (c >= M) return;
    float s = 0.f, q = 0.f;
    for (int r = 0; r < NREP; ++r) {
        s += cstatR[(long)r * 2 * M + c];
        q += cstatR[(long)r * 2 * M + M + c];
    }
    float m = s * invN, var = q * invN - m * m;
    float sa = rsqrtf(var + 1e-5f) * g[c];
    aff[c] = sa; aff[M + c] = b[c] - m * sa;
}

// ---------------------------------------------------------------------------
// CSR aggregation (one wave per node, grid-stride), 2-deep index prefetch.
// ---------------------------------------------------------------------------
template<int EB>
__global__ __launch_bounds__(256)
void csr_agg(const ushort_t* __restrict__ in, ushort_t* __restrict__ out,
             const int* __restrict__ offs, const int* __restrict__ elist,
             const int* __restrict__ esrc, const float* __restrict__ eattr,
             const float* __restrict__ Wb, const float* __restrict__ bb,
             const float* __restrict__ eps_p, int n_nodes)
{
    __shared__ float Ws[EB ? 4096 : 1];
    __shared__ float bs[EB ? 256 : 1];
    if (EB) {
        for (int i = threadIdx.x; i < 4096; i += 256) Ws[i] = Wb[i];
        bs[threadIdx.x] = bb[threadIdx.x];
        __syncthreads();
    }
    float epsv = 1.f + eps_p[0];
    int lane = threadIdx.x & 63;
    int gw = (blockIdx.x * 256 + threadIdx.x) >> 6;
    int nw = (gridDim.x * 256) >> 6;
    for (int u = gw; u < n_nodes; u += nw) {
        const ushort_t* own = in + (long)u * 256;
        float acc[4];
        #pragma unroll
        for (int j = 0; j < 4; ++j) acc[j] = epsv * h2f(own[lane + 64 * j]);
        int s = offs[u], e = offs[u + 1];
        int eid_n = 0, sid_n = 0;
        if (s < e) { eid_n = elist[s]; sid_n = esrc[eid_n]; }
        for (int i = s; i < e; ++i) {
            int eid = eid_n, sid = sid_n;
            if (i + 1 < e) { eid_n = elist[i + 1]; sid_n = esrc[eid_n]; }
            const ushort_t* row = in + (long)sid * 256;
            if (EB) {
                float ev[16];
                const float4* ea = (const float4*)(eattr + (long)eid * 16);
                float4 e0 = ea[0], e1 = ea[1], e2 = ea[2], e3 = ea[3];
                ev[0]=e0.x; ev[1]=e0.y; ev[2]=e0.z; ev[3]=e0.w;
                ev[4]=e1.x; ev[5]=e1.y; ev[6]=e1.z; ev[7]=e1.w;
                ev[8]=e2.x; ev[9]=e2.y; ev[10]=e2.z; ev[11]=e2.w;
                ev[12]=e3.x; ev[13]=e3.y; ev[14]=e3.z; ev[15]=e3.w;
                #pragma unroll
                for (int j = 0; j < 4; ++j) {
                    int c = lane + 64 * j;
                    float m = bs[c];
                    #pragma unroll
                    for (int k = 0; k < 16; ++k) m = fmaf(ev[k], Ws[k * 256 + c], m);
                    acc[j] += fmaxf(h2f(row[c]) + m, 0.f);
                }
            } else {
                #pragma unroll
                for (int j = 0; j < 4; ++j) acc[j] += h2f(row[lane + 64 * j]);
            }
        }
        ushort_t* o = out + (long)u * 256;
        #pragma unroll
        for (int j = 0; j < 4; ++j) o[lane + 64 * j] = f2h(acc[j]);
    }
}

// out[u] = relu(aff(raw[u])) + mean_{i in csr[u]} U[midx[elist[i]]]   (256 ch)
__global__ __launch_bounds__(128)
void csr_mean_aff(const ushort_t* __restrict__ raw, const ushort_t* __restrict__ U,
                  const int* __restrict__ midx, const int* __restrict__ elist,
                  const int* __restrict__ offs, const float* __restrict__ Aff,
                  ushort_t* __restrict__ outp)
{
    int u = blockIdx.x, t = threadIdx.x;
    int c0 = t * 2;
    float sa0 = Aff[c0], sa1 = Aff[c0 + 1], sb0 = Aff[256 + c0], sb1 = Aff[256 + c0 + 1];
    ushort2 b = *(const ushort2*)(raw + (long)u * 256 + c0);
    float x0 = fmaxf(h2f(b.x) * sa0 + sb0, 0.f);
    float x1 = fmaxf(h2f(b.y) * sa1 + sb1, 0.f);
    int s = offs[u], e = offs[u + 1];
    float a0 = 0.f, a1 = 0.f;
    long r_n = 0;
    if (s < e) r_n = midx[elist[s]];
    for (int i = s; i < e; ++i) {
        long r = r_n;
        if (i + 1 < e) r_n = midx[elist[i + 1]];
        ushort2 v = *(const ushort2*)(U + r * 256 + c0);
        a0 += h2f(v.x); a1 += h2f(v.y);
    }
    if (e > s) { float inv = 1.f / (float)(e - s); x0 += a0 * inv; x1 += a1 * inv; }
    ushort2 o; o.x = f2h(x0); o.y = f2h(x1);
    *(ushort2*)(outp + (long)u * 256 + c0) = o;
}

// ---------------------------------------------------------------------------
// fp32 GEMM for readout (small). LDA=133: conflict-free A-tile writes.
// ---------------------------------------------------------------------------
template<int RELU, typename TC>
__global__ __launch_bounds__(256)
void gemm_k(const float* __restrict__ A, const float* __restrict__ W,
            const float* __restrict__ bias, TC* __restrict__ C,
            int N, int K, int M)
{
    const int BK = 16, LDA = 133;
    __shared__ float As[BK * LDA];
    __shared__ float Bs[BK * LDA];
    const int brow = blockIdx.y * 128;
    const int bcol = blockIdx.x * 128;
    const int tid  = threadIdx.x;
    const int tr = tid >> 4, tc = tid & 15;

    float acc[8][8];
    #pragma unroll
    for (int i = 0; i < 8; ++i)
        #pragma unroll
        for (int j = 0; j < 8; ++j) acc[i][j] = 0.f;

    for (int k0 = 0; k0 < K; k0 += BK) {
        #pragma unroll
        for (int u = 0; u < 8; ++u) {
            int idx = tid + u * 256;
            int m = idx >> 4, kk = idx & 15;
            As[kk * LDA + m] = A[(long)(brow + m) * K + k0 + kk];
        }
        #pragma unroll
        for (int u = 0; u < 8; ++u) {
            int idx = tid + u * 256;
            int kk = idx >> 7, n = idx & 127;
            int col = bcol + n;
            Bs[kk * LDA + n] = (col < M) ? W[(long)(k0 + kk) * M + col] : 0.f;
        }
        __syncthreads();
        #pragma unroll
        for (int kk = 0; kk < BK; ++kk) {
            float av[8], bv[8];
            float4 a0 = *(const float4*)&As[kk * LDA + tr * 8];
            float4 a1 = *(const float4*)&As[kk * LDA + tr * 8 + 4];
            float4 b0 = *(const float4*)&Bs[kk * LDA + tc * 8];
            float4 b1 = *(const float4*)&Bs[kk * LDA + tc * 8 + 4];
            av[0]=a0.x; av[1]=a0.y; av[2]=a0.z; av[3]=a0.w;
            av[4]=a1.x; av[5]=a1.y; av[6]=a1.z; av[7]=a1.w;
            bv[0]=b0.x; bv[1]=b0.y; bv[2]=b0.z; bv[3]=b0.w;
            bv[4]=b1.x; bv[5]=b1.y; bv[6]=b1.z; bv[7]=b1.w;
            #pragma unroll
            for (int i = 0; i < 8; ++i)
                #pragma unroll
                for (int j = 0; j < 8; ++j)
                    acc[i][j] = fmaf(av[i], bv[j], acc[i][j]);
        }
        __syncthreads();
    }
    #pragma unroll
    for (int i = 0; i < 8; ++i) {
        int row = brow + tr * 8 + i;
        #pragma unroll
        for (int j = 0; j < 8; ++j) {
            int col = bcol + tc * 8 + j;
            if (col < M) {
                float v = acc[i][j] + bias[col];
                if (RELU) v = fmaxf(v, 0.f);
                if constexpr (sizeof(TC) == 2) ((ushort_t*)C)[(long)row * M + col] = f2h(v);
                else                           ((float*)C)[(long)row * M + col] = v;
            }
        }
    }
}

__global__ void count_idx(const int* __restrict__ idx, int n, int* __restrict__ cnt)
{
    int i = blockIdx.x * blockDim.x + threadIdx.x;
    if (i < n) atomicAdd(&cnt[idx[i]], 1);
}

// ---- parallel exclusive scan (3 phases) ----
__global__ __launch_bounds__(256)
void scan_p1(const int* __restrict__ cnt, int n, int* __restrict__ partials)
{
    __shared__ int sd[256];
    int i = blockIdx.x * 256 + threadIdx.x;
    sd[threadIdx.x] = (i < n) ? cnt[i] : 0;
    __syncthreads();
    #pragma unroll
    for (int s = 128; s > 0; s >>= 1) {
        if (threadIdx.x < s) sd[threadIdx.x] += sd[threadIdx.x + s];
        __syncthreads();
    }
    if (threadIdx.x == 0) partials[blockIdx.x] = sd[0];
}

__global__ __launch_bounds__(1024)
void scan_p2(int* __restrict__ partials, int nb, int* __restrict__ off, int n)
{
    __shared__ int sd[1024];
    int t = threadIdx.x;
    int v = (t < nb) ? partials[t] : 0;
    sd[t] = v;
    __syncthreads();
    for (int d = 1; d < 1024; d <<= 1) {
        int x = (t >= d) ? sd[t - d] : 0;
        __syncthreads();
        sd[t] += x;
        __syncthreads();
    }
    if (t < nb) partials[t] = sd[t] - v;
    if (t == 1023) off[n] = sd[nb - 1];
}

__global__ __launch_bounds__(256)
void scan_p3(const int* __restrict__ cnt, int n, const int* __restrict__ partials,
             int* __restrict__ off, int* __restrict__ cursor)
{
    __shared__ int sd[256];
    int i = blockIdx.x * 256 + threadIdx.x;
    int v = (i < n) ? cnt[i] : 0;
    sd[threadIdx.x] = v;
    __syncthreads();
    for (int d = 1; d < 256; d <<= 1) {
        int x = (threadIdx.x >= d) ? sd[threadIdx.x - d] : 0;
        __syncthreads();
        sd[threadIdx.x] += x;
        __syncthreads();
    }
    if (i < n) {
        int e = partials[blockIdx.x] + sd[threadIdx.x] - v;
        off[i] = e; cursor[i] = e;
    }
}

__global__ void csr_fill(const int* __restrict__ idx, int n,
                         int* __restrict__ cursor, int* __restrict__ elist)
{
    int i = blockIdx.x * blockDim.x + threadIdx.x;
    if (i < n) { int p = atomicAdd(&cursor[idx[i]], 1); elist[p] = i; }
}

__global__ __launch_bounds__(256)
void seg_pool(const ushort_t* __restrict__ X, const int* __restrict__ bidx,
              int nrows, float* __restrict__ pooled)
{
    int b = blockIdx.x, t = threadIdx.x;
    int lo = 0, hi = nrows;
    while (lo < hi) { int mid = (lo + hi) >> 1; if (bidx[mid] < b) lo = mid + 1; else hi = mid; }
    int s = lo; hi = nrows;
    while (lo < hi) { int mid = (lo + hi) >> 1; if (bidx[mid] < b + 1) lo = mid + 1; else hi = mid; }
    int e = lo;
    float acc = 0.f;
    for (int r = s; r < e; ++r) acc += h2f(X[(long)r * 256 + t]);
    pooled[(long)b * 256 + t] = acc / fmaxf((float)(e - s), 1.f);
}

__global__ void vadd(float* __restrict__ out, const float* __restrict__ in, long n4)
{
    long t = (long)blockIdx.x * blockDim.x + threadIdx.x;
    if (t >= n4) return;
    float4 a = ((float4*)out)[t];
    float4 b = ((const float4*)in)[t];
    a.x += b.x; a.y += b.y; a.z += b.z; a.w += b.w;
    ((float4*)out)[t] = a;
}

// ---------------------------------------------------------------------------
extern "C" void kernel_launch(void* const* d_in, const int* in_sizes, int n_in,
                              void* d_out, int out_size, void* d_ws, size_t ws_size,
                              hipStream_t stream)
{
    (void)in_sizes; (void)n_in;
    const float* x          = (const float*)d_in[0];
    const float* fragments  = (const float*)d_in[1];
    const float* edge_attr  = (const float*)d_in[2];
    const float* atom_enc_W = (const float*)d_in[3];
    const float* atom_enc_b = (const float*)d_in[4];
    const float* frag_enc_W = (const float*)d_in[5];
    const float* frag_enc_b = (const float*)d_in[6];
    const float* bond_W     = (const float*)d_in[7];
    const float* bond_b     = (const float*)d_in[8];
    const float* gine_eps   = (const float*)d_in[9];
    const float* gine_W1    = (const float*)d_in[10];
    const float* gine_b1    = (const float*)d_in[11];
    const float* gine_bn_g  = (const float*)d_in[12];
    const float* gine_bn_b  = (const float*)d_in[13];
    const float* gine_W2    = (const float*)d_in[14];
    const float* gine_b2    = (const float*)d_in[15];
    const float* atom_bn_g  = (const float*)d_in[16];
    const float* atom_bn_b  = (const float*)d_in[17];
    const float* gin_eps    = (const float*)d_in[18];
    const float* gin_W1     = (const float*)d_in[19];
    const float* gin_b1     = (const float*)d_in[20];
    const float* gin_bn_g   = (const float*)d_in[21];
    const float* gin_bn_b   = (const float*)d_in[22];
    const float* gin_W2     = (const float*)d_in[23];
    const float* gin_b2     = (const float*)d_in[24];
    const float* frag_bn_g  = (const float*)d_in[25];
    const float* frag_bn_b  = (const float*)d_in[26];
    const float* a2f_W      = (const float*)d_in[27];
    const float* a2f_b      = (const float*)d_in[28];
    const float* f2a_W      = (const float*)d_in[29];
    const float* f2a_b      = (const float*)d_in[30];
    const float* fo_W1      = (const float*)d_in[31];
    const float* fo_b1      = (const float*)d_in[32];
    const float* fo_W2      = (const float*)d_in[33];
    const float* fo_b2      = (const float*)d_in[34];
    const float* ao_W1      = (const float*)d_in[35];
    const float* ao_b1      = (const float*)d_in[36];
    const float* ao_W2      = (const float*)d_in[37];
    const float* ao_b2      = (const float*)d_in[38];
    const float* out_W1     = (const float*)d_in[39];
    const float* out_b1     = (const float*)d_in[40];
    const float* out_W2     = (const float*)d_in[41];
    const float* out_b2     = (const float*)d_in[42];
    const int* edge_index   = (const int*)d_in[43];
    const int* fedge_index  = (const int*)d_in[44];
    const int* batch        = (const int*)d_in[45];
    const int* fbatch       = (const int*)d_in[46];
    const int* mem_atom     = (const int*)d_in[47];
    const int* mem_frag     = (const int*)d_in[48];

    const int* src  = edge_index;
    const int* dst  = edge_index + N_EDGE;
    const int* fsrc = fedge_index;
    const int* fdst = fedge_index + N_FEDGE;

    // ---- arena ----
    const size_t WPN = 2646016;
    size_t off = 0;
    auto take = [&](size_t b) -> size_t { size_t p = off; off = (off + b + 255) & ~(size_t)255; return p; };
    size_t o_big   = take((size_t)N_ATOM * 512 * 2);     // 134 MB
    size_t o_a     = take((size_t)N_ATOM * H * 2);       // 67 MB
    size_t o_f     = take((size_t)N_FRAG * H * 2);
    size_t o_f2    = take((size_t)N_FRAG * H * 2);
    size_t o_offea = take((size_t)(N_ATOM + 1) * 4);
    size_t o_elea  = take((size_t)N_EDGE * 4);
    size_t o_offef = take((size_t)(N_FRAG + 1) * 4);
    size_t o_elef  = take((size_t)N_FEDGE * 4);
    size_t o_offma = take((size_t)(N_ATOM + 1) * 4);
    size_t o_elma  = take((size_t)N_MEM * 4);
    size_t o_offmf = take((size_t)(N_FRAG + 1) * 4);
    size_t o_elmf  = take((size_t)N_MEM * 4);
    size_t o_cnta  = take((size_t)N_ATOM * 4);
    size_t o_cntf  = take((size_t)N_FRAG * 4);
    size_t o_part  = take(1024 * 4);
    size_t o_stats = take((size_t)NREP * 3072 * 4);
    size_t o_aff   = take(3072 * 4);
    size_t o_hi    = take(WPN * 2);
    size_t need = off;

    if (need > ws_size) {
        fill_const<<<64, 256, 0, stream>>>((float*)d_out, out_size,
                                           (float)((double)ws_size / 1024.0));
        return;
    }
    char* base = (char*)d_ws;
    char*     big     = base + o_big;
    ushort_t* a       = (ushort_t*)(base + o_a);
    ushort_t* f       = (ushort_t*)(base + o_f);
    ushort_t* f2      = (ushort_t*)(base + o_f2);
    int* off_ea = (int*)(base + o_offea);
    int* el_ea  = (int*)(base + o_elea);
    int* off_ef = (int*)(base + o_offef);
    int* el_ef  = (int*)(base + o_elef);
    int* off_ma = (int*)(base + o_offma);
    int* el_ma  = (int*)(base + o_elma);
    int* off_mf = (int*)(base + o_offmf);
    int* el_mf  = (int*)(base + o_elmf);
    int* cnt_a  = (int*)(base + o_cnta);
    int* cnt_f  = (int*)(base + o_cntf);
    int* parts  = (int*)(base + o_part);
    float* statsR = (float*)(base + o_stats);
    float* affs   = (float*)(base + o_aff);
    ushort_t* Wp_hi = (ushort_t*)(base + o_hi);

    float* cst1a = statsR;
    float* cst2a = statsR + (size_t)NREP * 1024;
    float* cst1f = statsR + (size_t)NREP * 1536;
    float* cst2f = statsR + (size_t)NREP * 2560;
    float* aff1_a = affs;
    float* aff2_a = affs + 1024;
    float* aff1_f = affs + 1536;
    float* aff2_f = affs + 2560;

    ushort_t* big_u = (ushort_t*)big;
    const size_t HALF_U = (size_t)N_ATOM * 256;
    ushort_t* ha  = big_u + HALF_U;
    const size_t PAN_A = (size_t)N_ATOM * 128;
    const size_t PAN_F = (size_t)N_FRAG * 128;
    ushort_t* Ua = big_u;
    float* pooled_f = (float*)big;
    float* pooled_a = (float*)(big + (size_t)8 * 1024 * 1024);
    float* tmp      = (float*)(big + (size_t)16 * 1024 * 1024);
    ushort_t* xh = big_u;
    ushort_t* fh = big_u + (size_t)N_ATOM * 64;

    const long WG0 = 0, WG1 = 524288, WG2 = 1048576, WG3 = 1572864,
               WG4 = 2097152, WG5 = 2359296, WG6 = 2621440, WG7 = 2637824;

    auto build_csr = [&](const int* idx, int n_edges, int n_nodes,
                         int* cnt, int* offs, int* elist) {
        hipMemsetAsync(cnt, 0, (size_t)n_nodes * 4, stream);
        count_idx<<<CDIV(n_edges,256),256,0,stream>>>(idx, n_edges, cnt);
        int nb = CDIV(n_nodes, 256);
        scan_p1<<<nb, 256, 0, stream>>>(cnt, n_nodes, parts);
        scan_p2<<<1, 1024, 0, stream>>>(parts, nb, offs, n_nodes);
        scan_p3<<<nb, 256, 0, stream>>>(cnt, n_nodes, parts, offs, cnt);
        csr_fill<<<CDIV(n_edges,256),256,0,stream>>>(idx, n_edges, cnt, elist);
    };

    // ---- weight prep + CSR builds ----
    prep_w<<<CDIV((long)WPN, 256), 256, 0, stream>>>(gine_W1, gine_W2, gin_W1, gin_W2,
                                                     a2f_W, f2a_W, atom_enc_W, frag_enc_W,
                                                     Wp_hi);
    build_csr(dst,      N_EDGE,  N_ATOM, cnt_a, off_ea, el_ea);
    build_csr(fdst,     N_FEDGE, N_FRAG, cnt_f, off_ef, el_ef);
    build_csr(mem_atom, N_MEM,   N_ATOM, cnt_a, off_ma, el_ma);
    build_csr(mem_frag, N_MEM,   N_FRAG, cnt_f, off_mf, el_mf);

    // ---- encoders via MFMA (f16 inputs staged in big) ----
    conv_f2h<<<2048, 256, 0, stream>>>(x, xh, (long)N_ATOM * 64);
    conv_f2h<<<512, 256, 0, stream>>>(fragments, fh, (long)N_FRAG * 32);
    {
        PanelsIn Ein; PanelsOut Eout;
        for (int i = 0; i < 4; ++i) Ein.p[i] = xh;
        Eout.p[0] = a; Eout.p[1] = a + 128; Eout.p[2] = a; Eout.p[3] = a;
        mfma_gemm<0><<<dim3(2, N_ATOM/128), 256, 0, stream>>>(
            Ein, 64, Wp_hi + WG6, atom_enc_b, Eout, 256, nullptr, nullptr,
            N_ATOM, 64, 256);
        PanelsIn Fin; PanelsOut Fout;
        for (int i = 0; i < 4; ++i) Fin.p[i] = fh;
        Fout.p[0] = f; Fout.p[1] = f + 128; Fout.p[2] = f; Fout.p[3] = f;
        mfma_gemm<0><<<dim3(2, N_FRAG/128), 256, 0, stream>>>(
            Fin, 32, Wp_hi + WG7, frag_enc_b, Fout, 256, nullptr, nullptr,
            N_FRAG, 32, 256);
    }

    const float invNA = 1.f / N_ATOM, invNF = 1.f / N_FRAG;

    for (int l = 0; l < 4; ++l) {
        hipMemsetAsync(statsR, 0, (size_t)NREP * 3072 * 4, stream);

        // ===== atoms: GINE + MLP =====
        csr_agg<1><<<2048, 256, 0, stream>>>(a, ha, off_ea, el_ea, src, edge_attr,
            bond_W + (long)l*16*H, bond_b + l*H, gine_eps + l, N_ATOM);

        PanelsIn A1in; PanelsOut A1out;
        for (int i = 0; i < 4; ++i) A1in.p[i] = ha + i * 128;
        A1out.p[0] = a;          A1out.p[1] = a + PAN_A;
        A1out.p[2] = big_u;      A1out.p[3] = big_u + PAN_A;
        mfma_gemm<0><<<dim3(4, N_ATOM/128), 256, 0, stream>>>(
            A1in, 256, Wp_hi + WG0 + (long)l*131072,
            gine_b1 + l*512, A1out, 128, nullptr, cst1a, N_ATOM, 256, 512);
        finalize_aff<<<2, 256, 0, stream>>>(cst1a, 512, invNA,
            gine_bn_g + l*512, gine_bn_b + l*512, aff1_a);

        PanelsIn A2in; PanelsOut A2out;
        A2in.p[0] = a;       A2in.p[1] = a + PAN_A;
        A2in.p[2] = big_u;   A2in.p[3] = big_u + PAN_A;
        A2out.p[0] = ha; A2out.p[1] = ha + 128; A2out.p[2] = ha; A2out.p[3] = ha;
        mfma_gemm<0><<<dim3(2, N_ATOM/128), 256, 0, stream>>>(
            A2in, 128, Wp_hi + WG1 + (long)l*131072,
            gine_b2 + l*H, A2out, 256, aff1_a, cst2a, N_ATOM, 512, 256);
        finalize_aff<<<1, 256, 0, stream>>>(cst2a, 256, invNA,
            atom_bn_g + l*H, atom_bn_b + l*H, aff2_a);

        // ===== fragments: GIN + MLP =====
        csr_agg<0><<<512, 256, 0, stream>>>(f, f2, off_ef, el_ef, fsrc, nullptr,
            nullptr, nullptr, gin_eps + l, N_FRAG);

        PanelsIn F1in; PanelsOut F1out;
        for (int i = 0; i < 4; ++i) F1in.p[i] = f2 + i * 128;
        for (int i = 0; i < 4; ++i) F1out.p[i] = big_u + i * PAN_F;
        mfma_gemm<0><<<dim3(4, N_FRAG/128), 256, 0, stream>>>(
            F1in, 256, Wp_hi + WG2 + (long)l*131072,
            gin_b1 + l*512, F1out, 128, nullptr, cst1f, N_FRAG, 256, 512);
        finalize_aff<<<2, 256, 0, stream>>>(cst1f, 512, invNF,
            gin_bn_g + l*512, gin_bn_b + l*512, aff1_f);

        PanelsIn F2in; PanelsOut F2out;
        for (int i = 0; i < 4; ++i) F2in.p[i] = big_u + i * PAN_F;
        F2out.p[0] = f2; F2out.p[1] = f2 + 128; F2out.p[2] = f2; F2out.p[3] = f2;
        mfma_gemm<0><<<dim3(2, N_FRAG/128), 256, 0, stream>>>(
            F2in, 128, Wp_hi + WG3 + (long)l*131072,
            gin_b2 + l*H, F2out, 256, aff1_f, cst2f, N_FRAG, 512, 256);
        finalize_aff<<<1, 256, 0, stream>>>(cst2f, 256, invNF,
            frag_bn_g + l*H, frag_bn_b + l*H, aff2_f);

        // ===== inter MP =====
        PanelsIn UAin; PanelsOut UAout;
        for (int i = 0; i < 4; ++i) UAin.p[i] = ha + i * 128;
        UAout.p[0] = Ua; UAout.p[1] = Ua + 128; UAout.p[2] = Ua; UAout.p[3] = Ua;
        mfma_gemm<1><<<dim3(2, N_ATOM/128), 256, 0, stream>>>(
            UAin, 256, Wp_hi + WG4 + (long)l*65536,
            a2f_b + l*H, UAout, 256, aff2_a, nullptr, N_ATOM, 256, 256);
        csr_mean_aff<<<N_FRAG, 128, 0, stream>>>(f2, Ua, mem_atom, el_mf, off_mf,
                                                 aff2_f, f);
        PanelsIn UFin; PanelsOut UFout;
        for (int i = 0; i < 4; ++i) UFin.p[i] = f + i * 128;
        UFout.p[0] = f2; UFout.p[1] = f2 + 128; UFout.p[2] = f2; UFout.p[3] = f2;
        mfma_gemm<1><<<dim3(2, N_FRAG/128), 256, 0, stream>>>(
            UFin, 256, Wp_hi + WG5 + (long)l*65536,
            f2a_b + l*H, UFout, 256, nullptr, nullptr, N_FRAG, 256, 256);
        csr_mean_aff<<<N_ATOM, 128, 0, stream>>>(ha, f2, mem_frag, el_ma, off_ma,
                                                 aff2_a, a);
    }

    // ===== readout =====
    seg_pool<<<BATCH, 256, 0, stream>>>(f, fbatch, N_FRAG, pooled_f);
    gemm_k<1,float><<<dim3(2, BATCH/128), 256, 0, stream>>>(
        pooled_f, fo_W1, fo_b1, tmp, BATCH, H, H);
    gemm_k<1,float><<<dim3(2, BATCH/128), 256, 0, stream>>>(
        tmp, fo_W2, fo_b2, pooled_f, BATCH, H, H);

    seg_pool<<<BATCH, 256, 0, stream>>>(a, batch, N_ATOM, pooled_a);
    gemm_k<1,float><<<dim3(2, BATCH/128), 256, 0, stream>>>(
        pooled_a, ao_W1, ao_b1, tmp, BATCH, H, H);
    gemm_k<1,float><<<dim3(2, BATCH/128), 256, 0, stream>>>(
        tmp, ao_W2, ao_b2, pooled_a, BATCH, H, H);

    vadd<<<(int)CDIV((long)BATCH*H/4,256), 256, 0, stream>>>(
        pooled_a, pooled_f, (long)BATCH * H / 4);
    gemm_k<1,float><<<dim3(2, BATCH/128), 256, 0, stream>>>(
        pooled_a, out_W1, out_b1, tmp, BATCH, H, H);
    gemm_k<0,float><<<dim3(1, BATCH/128), 256, 0, stream>>>(
        tmp, out_W2, out_b2, (float*)d_out, BATCH, H, 1);
}